// Round 1
// baseline (4812.540 us; speedup 1.0000x reference)
//
#include <hip/hip_runtime.h>
#include <math.h>

#define HW_ 17424
#define WID 132
#define HGT 132
#define CH 256
#define MROWS 139392          // 8*17424
#define OUTOFF 35684352       // 8*256*17424

// ---------------------------------------------------------------------------
// LayerNorm over channels with BCHW -> (M,256) transpose.
// Block: 256 threads (= channels), handles 4 consecutive hw positions.
// ---------------------------------------------------------------------------
__global__ __launch_bounds__(256)
void ln_k(const float* __restrict__ x, const float* __restrict__ w,
          const float* __restrict__ bias, float* __restrict__ out) {
    __shared__ float4 s1[256];
    __shared__ float4 s2[256];
    const int tid = threadIdx.x;              // channel
    const int b   = blockIdx.y;
    const int hw0 = blockIdx.x << 2;          // 4 positions
    const float* px = x + ((size_t)(b * CH + tid)) * HW_ + hw0;
    float4 v = *(const float4*)px;
    s1[tid] = v;
    s2[tid] = make_float4(v.x * v.x, v.y * v.y, v.z * v.z, v.w * v.w);
    __syncthreads();
    for (int off = 128; off > 0; off >>= 1) {
        if (tid < off) {
            float4 a = s1[tid], c = s1[tid + off];
            a.x += c.x; a.y += c.y; a.z += c.z; a.w += c.w;
            s1[tid] = a;
            float4 d = s2[tid], e = s2[tid + off];
            d.x += e.x; d.y += e.y; d.z += e.z; d.w += e.w;
            s2[tid] = d;
        }
        __syncthreads();
    }
    float4 sum = s1[0], sq = s2[0];
    const float wv = w[tid], bv = bias[tid];
    const float inv = 1.0f / 256.0f;
    float o[4];
    {
        float m = sum.x * inv; float var = sq.x * inv - m * m;
        o[0] = (v.x - m) * rsqrtf(var + 1e-6f) * wv + bv;
    }
    {
        float m = sum.y * inv; float var = sq.y * inv - m * m;
        o[1] = (v.y - m) * rsqrtf(var + 1e-6f) * wv + bv;
    }
    {
        float m = sum.z * inv; float var = sq.z * inv - m * m;
        o[2] = (v.z - m) * rsqrtf(var + 1e-6f) * wv + bv;
    }
    {
        float m = sum.w * inv; float var = sq.w * inv - m * m;
        o[3] = (v.w - m) * rsqrtf(var + 1e-6f) * wv + bv;
    }
    float* po = out + ((size_t)(b * HW_ + hw0)) * CH + tid;
    po[0] = o[0]; po[256] = o[1]; po[512] = o[2]; po[768] = o[3];
}

// ---------------------------------------------------------------------------
// Tiled fp32 GEMM: C[M,N] = epi(A[M,K] @ W[K,N] + bias)
// BM=128, BN=64, BK=16, 256 threads, 8x4 micro-tile.
// EPI: 0 = none, 1 = exact GELU, 2 = multiply by mulbuf (in-place q*e)
// M assumed multiple of 128 (139392 = 1089*128), K,N multiples of 16/64.
// ---------------------------------------------------------------------------
template <int EPI>
__global__ __launch_bounds__(256)
void gemm_k(const float* __restrict__ A, const float* __restrict__ W,
            const float* __restrict__ bias, float* __restrict__ C,
            const float* __restrict__ mulbuf, int K, int N) {
    __shared__ float As[16][132];   // +4 pad: 2-way max on read/write
    __shared__ float Bs[16][64];
    const int tid  = threadIdx.x;
    const int row0 = blockIdx.x * 128;
    const int col0 = blockIdx.y * 64;
    const int tn = tid & 15;        // N micro (4 cols)
    const int tm = tid >> 4;        // M micro (8 rows)
    const int arow = tid >> 2;      // 0..63
    const int akk  = (tid & 3) << 2;
    const int bkr  = tid >> 4;      // 0..15
    const int bnn  = (tid & 15) << 2;

    const float* Ap0 = A + (size_t)(row0 + arow) * K + akk;
    const float* Ap1 = Ap0 + (size_t)64 * K;
    const float* Wp  = W + (size_t)bkr * N + col0 + bnn;

    float acc[8][4];
#pragma unroll
    for (int i = 0; i < 8; ++i)
#pragma unroll
        for (int j = 0; j < 4; ++j) acc[i][j] = 0.f;

    for (int kt = 0; kt < K; kt += 16) {
        float4 a0 = *(const float4*)(Ap0 + kt);
        float4 a1 = *(const float4*)(Ap1 + kt);
        float4 bv = *(const float4*)(Wp + (size_t)kt * N);
        __syncthreads();
        As[akk + 0][arow] = a0.x; As[akk + 1][arow] = a0.y;
        As[akk + 2][arow] = a0.z; As[akk + 3][arow] = a0.w;
        As[akk + 0][arow + 64] = a1.x; As[akk + 1][arow + 64] = a1.y;
        As[akk + 2][arow + 64] = a1.z; As[akk + 3][arow + 64] = a1.w;
        *(float4*)&Bs[bkr][bnn] = bv;
        __syncthreads();
#pragma unroll
        for (int k = 0; k < 16; ++k) {
            float4 av0 = *(const float4*)&As[k][tm << 3];
            float4 av1 = *(const float4*)&As[k][(tm << 3) + 4];
            float4 b4  = *(const float4*)&Bs[k][tn << 2];
            float am[8] = {av0.x, av0.y, av0.z, av0.w, av1.x, av1.y, av1.z, av1.w};
            float bm[4] = {b4.x, b4.y, b4.z, b4.w};
#pragma unroll
            for (int i = 0; i < 8; ++i)
#pragma unroll
                for (int j = 0; j < 4; ++j) acc[i][j] += am[i] * bm[j];
        }
    }
    float4 bb = *(const float4*)&bias[col0 + (tn << 2)];
    float bias4[4] = {bb.x, bb.y, bb.z, bb.w};
#pragma unroll
    for (int i = 0; i < 8; ++i) {
        const int row = row0 + (tm << 3) + i;
        const size_t off = (size_t)row * N + col0 + (tn << 2);
        float4 r;
        float* rp = &r.x;
#pragma unroll
        for (int j = 0; j < 4; ++j) {
            float v = acc[i][j] + bias4[j];
            if (EPI == 1) v = 0.5f * v * (1.0f + erff(v * 0.7071067811865475f));
            rp[j] = v;
        }
        if (EPI == 2) {
            float4 qv = *(const float4*)(mulbuf + off);
            r.x *= qv.x; r.y *= qv.y; r.z *= qv.z; r.w *= qv.w;
        }
        *(float4*)(C + off) = r;
    }
}

// ---------------------------------------------------------------------------
// Final projection: cat = [g | l1 | l2] (each M x 128), N=512 = [proj | proje],
// output written transposed to BCHW into d_out (out first, out_e at OUTOFF).
// ---------------------------------------------------------------------------
__global__ __launch_bounds__(256)
void gemm_proj_k(const float* __restrict__ g, const float* __restrict__ l1,
                 const float* __restrict__ l2,
                 const float* __restrict__ w1, const float* __restrict__ b1,
                 const float* __restrict__ w2, const float* __restrict__ b2,
                 float* __restrict__ out) {
    __shared__ float As[16][132];
    __shared__ float Bs[16][64];
    const int tid  = threadIdx.x;
    const int row0 = blockIdx.x * 128;
    const int col0 = blockIdx.y * 64;       // 0..448
    const int half  = col0 >> 8;            // 0 -> proj, 1 -> proje
    const int ncol0 = col0 & 255;
    const float* Wsel = half ? w2 : w1;
    const float* bsel = half ? b2 : b1;
    float* obase = out + (half ? (size_t)OUTOFF : (size_t)0);

    const int tn = tid & 15;
    const int tm = tid >> 4;
    const int arow = tid >> 2;
    const int akk  = (tid & 3) << 2;
    const int bkr  = tid >> 4;
    const int bnn  = (tid & 15) << 2;

    float acc[8][4];
#pragma unroll
    for (int i = 0; i < 8; ++i)
#pragma unroll
        for (int j = 0; j < 4; ++j) acc[i][j] = 0.f;

    for (int kt = 0; kt < 384; kt += 16) {
        const float* Ab = (kt < 128) ? g : (kt < 256) ? l1 : l2;
        const int kloc = kt & 127;
        float4 a0 = *(const float4*)(Ab + (size_t)(row0 + arow) * 128 + kloc + akk);
        float4 a1 = *(const float4*)(Ab + (size_t)(row0 + arow + 64) * 128 + kloc + akk);
        float4 bv = *(const float4*)(Wsel + (size_t)(kt + bkr) * 256 + ncol0 + bnn);
        __syncthreads();
        As[akk + 0][arow] = a0.x; As[akk + 1][arow] = a0.y;
        As[akk + 2][arow] = a0.z; As[akk + 3][arow] = a0.w;
        As[akk + 0][arow + 64] = a1.x; As[akk + 1][arow + 64] = a1.y;
        As[akk + 2][arow + 64] = a1.z; As[akk + 3][arow + 64] = a1.w;
        *(float4*)&Bs[bkr][bnn] = bv;
        __syncthreads();
#pragma unroll
        for (int k = 0; k < 16; ++k) {
            float4 av0 = *(const float4*)&As[k][tm << 3];
            float4 av1 = *(const float4*)&As[k][(tm << 3) + 4];
            float4 b4  = *(const float4*)&Bs[k][tn << 2];
            float am[8] = {av0.x, av0.y, av0.z, av0.w, av1.x, av1.y, av1.z, av1.w};
            float bm[4] = {b4.x, b4.y, b4.z, b4.w};
#pragma unroll
            for (int i = 0; i < 8; ++i)
#pragma unroll
                for (int j = 0; j < 4; ++j) acc[i][j] += am[i] * bm[j];
        }
    }
    float4 bb = *(const float4*)&bsel[ncol0 + (tn << 2)];
    float bias4[4] = {bb.x, bb.y, bb.z, bb.w};
#pragma unroll
    for (int i = 0; i < 8; ++i) {
        const int row = row0 + (tm << 3) + i;
        const int bidx = row / HW_;
        const int hw = row - bidx * HW_;
#pragma unroll
        for (int j = 0; j < 4; ++j) {
            const int c = ncol0 + (tn << 2) + j;
            obase[((size_t)(bidx * 256 + c)) * HW_ + hw] = acc[i][j] + bias4[j];
        }
    }
}

// ---------------------------------------------------------------------------
// 22x22 blocked mean pool of cat([xcl, xel]) -> pooled (B,36,512)
// ---------------------------------------------------------------------------
__global__ __launch_bounds__(256)
void pool_k(const float* __restrict__ xcl, const float* __restrict__ xel,
            float* __restrict__ pooled) {
    const int q = blockIdx.x;   // 0..35
    const int b = blockIdx.y;
    const int wi = q / 6, wj = q % 6;
    const int tid = threadIdx.x;   // 256 channels each of two tensors
    const size_t base = ((size_t)(b * HW_ + wi * 22 * WID + wj * 22)) * CH + tid;
    const float* p0 = xcl + base;
    const float* p1 = xel + base;
    float s0 = 0.f, s1 = 0.f;
    for (int iy = 0; iy < 22; ++iy) {
        const size_t ro = (size_t)iy * WID * CH;
        for (int ix = 0; ix < 22; ++ix) {
            const size_t off = ro + (size_t)ix * CH;
            s0 += p0[off];
            s1 += p1[off];
        }
    }
    const float inv = 1.0f / 484.0f;
    float* dst = pooled + (size_t)(b * 36 + q) * 512;
    dst[tid] = s0 * inv;
    dst[256 + tid] = s1 * inv;
}

// ---------------------------------------------------------------------------
// m = pooled @ xe_w + xe_b  (rows = 288, K = 512, N = 128)
// ---------------------------------------------------------------------------
__global__ __launch_bounds__(128)
void mproj_k(const float* __restrict__ pooled, const float* __restrict__ xe_w,
             const float* __restrict__ xe_b, float* __restrict__ mbuf) {
    __shared__ float p[512];
    const int q = blockIdx.x, b = blockIdx.y, tid = threadIdx.x;
    const float* prow = pooled + (size_t)(b * 36 + q) * 512;
    for (int i = tid; i < 512; i += 128) p[i] = prow[i];
    __syncthreads();
    float acc = xe_b[tid];
    for (int k = 0; k < 512; ++k) acc += p[k] * xe_w[k * 128 + tid];
    mbuf[(size_t)(b * 36 + q) * 128 + tid] = acc;
}

// ---------------------------------------------------------------------------
// Attention: one block per (b, head, q). Online softmax over HW_ keys.
// kv layout: row-major (M,256); k = cols [head*16,+16), v = cols [128+head*16,+16)
// ---------------------------------------------------------------------------
__global__ __launch_bounds__(256)
void attn_k(const float* __restrict__ mbuf, const float* __restrict__ kv,
            float* __restrict__ aout) {
    const int q = blockIdx.x, head = blockIdx.y, b = blockIdx.z;
    const int tid = threadIdx.x;
    const float* mv = mbuf + (size_t)(b * 36 + q) * 128 + head * 16;
    float4 m0 = *(const float4*)(mv + 0);
    float4 m1 = *(const float4*)(mv + 4);
    float4 m2 = *(const float4*)(mv + 8);
    float4 m3 = *(const float4*)(mv + 12);
    float mx = -INFINITY, sum = 0.f;
    float4 a0 = {0, 0, 0, 0}, a1 = {0, 0, 0, 0}, a2 = {0, 0, 0, 0}, a3 = {0, 0, 0, 0};
    for (int j = tid; j < HW_; j += 256) {
        const float* row = kv + ((size_t)(b * HW_ + j)) * 256 + head * 16;
        float4 k0 = *(const float4*)(row + 0);
        float4 k1 = *(const float4*)(row + 4);
        float4 k2 = *(const float4*)(row + 8);
        float4 k3 = *(const float4*)(row + 12);
        float s = m0.x * k0.x + m0.y * k0.y + m0.z * k0.z + m0.w * k0.w
                + m1.x * k1.x + m1.y * k1.y + m1.z * k1.z + m1.w * k1.w
                + m2.x * k2.x + m2.y * k2.y + m2.z * k2.z + m2.w * k2.w
                + m3.x * k3.x + m3.y * k3.y + m3.z * k3.z + m3.w * k3.w;
        s *= 0.25f;   // d^-0.5, d=16
        const float nm = fmaxf(mx, s);
        const float corr = expf(mx - nm);
        const float p = expf(s - nm);
        sum = sum * corr + p;
        const float* vr = row + 128;
        float4 v0 = *(const float4*)(vr + 0);
        float4 v1 = *(const float4*)(vr + 4);
        float4 v2 = *(const float4*)(vr + 8);
        float4 v3 = *(const float4*)(vr + 12);
        a0.x = a0.x * corr + p * v0.x; a0.y = a0.y * corr + p * v0.y;
        a0.z = a0.z * corr + p * v0.z; a0.w = a0.w * corr + p * v0.w;
        a1.x = a1.x * corr + p * v1.x; a1.y = a1.y * corr + p * v1.y;
        a1.z = a1.z * corr + p * v1.z; a1.w = a1.w * corr + p * v1.w;
        a2.x = a2.x * corr + p * v2.x; a2.y = a2.y * corr + p * v2.y;
        a2.z = a2.z * corr + p * v2.z; a2.w = a2.w * corr + p * v2.w;
        a3.x = a3.x * corr + p * v3.x; a3.y = a3.y * corr + p * v3.y;
        a3.z = a3.z * corr + p * v3.z; a3.w = a3.w * corr + p * v3.w;
        mx = nm;
    }
    __shared__ float smax[256];
    __shared__ float ssum[256];
    __shared__ float sacc[256][16];
    smax[tid] = mx; ssum[tid] = sum;
    float* sa = sacc[tid];
    sa[0] = a0.x; sa[1] = a0.y; sa[2] = a0.z; sa[3] = a0.w;
    sa[4] = a1.x; sa[5] = a1.y; sa[6] = a1.z; sa[7] = a1.w;
    sa[8] = a2.x; sa[9] = a2.y; sa[10] = a2.z; sa[11] = a2.w;
    sa[12] = a3.x; sa[13] = a3.y; sa[14] = a3.z; sa[15] = a3.w;
    for (int off = 128; off > 0; off >>= 1) {
        __syncthreads();
        if (tid < off) {
            const float ma = smax[tid], mb = smax[tid + off];
            const float nm = fmaxf(ma, mb);
            const float ea = expf(ma - nm), eb = expf(mb - nm);
            ssum[tid] = ssum[tid] * ea + ssum[tid + off] * eb;
            for (int i = 0; i < 16; ++i)
                sacc[tid][i] = sacc[tid][i] * ea + sacc[tid + off][i] * eb;
            smax[tid] = nm;
        }
    }
    __syncthreads();
    if (tid < 16)
        aout[((size_t)(b * 8 + head) * 36 + q) * 16 + tid] = sacc[0][tid] / ssum[0];
}

// ---------------------------------------------------------------------------
// Bilinear upsample 6x6 -> 132x132 (half-pixel, edge clamp == jax renorm).
// aout: (B, 8 heads, 36, 16) ; write g as (M,128), channel = head*16+di
// ---------------------------------------------------------------------------
__global__ __launch_bounds__(256)
void upsample_k(const float* __restrict__ aout, float* __restrict__ g) {
    const int tid = threadIdx.x;
    const int c = tid & 127;
    const int hw = blockIdx.x * 2 + (tid >> 7);
    const int b = blockIdx.y;
    const int h = hw / WID;
    const int w = hw - h * WID;
    const float fy = (h - 10.5f) * (1.0f / 22.0f);
    const float fx = (w - 10.5f) * (1.0f / 22.0f);
    float y0f = floorf(fy), x0f = floorf(fx);
    const float ty = fy - y0f, tx = fx - x0f;
    int y0 = (int)y0f, x0 = (int)x0f;
    int y1 = min(y0 + 1, 5), x1 = min(x0 + 1, 5);
    y0 = max(y0, 0); x0 = max(x0, 0);
    const int head = c >> 4, di = c & 15;
    const float* src = aout + ((size_t)(b * 8 + head) * 36) * 16 + di;
    const float s00 = src[(y0 * 6 + x0) * 16];
    const float s01 = src[(y0 * 6 + x1) * 16];
    const float s10 = src[(y1 * 6 + x0) * 16];
    const float s11 = src[(y1 * 6 + x1) * 16];
    const float v = (1.f - ty) * ((1.f - tx) * s00 + tx * s01)
                  + ty * ((1.f - tx) * s10 + tx * s11);
    g[((size_t)(b * HW_ + hw)) * 128 + c] = v;
}

// ---------------------------------------------------------------------------
// Depthwise 7x7 conv, pad 3, channels-last (M,128), + bias.
// ---------------------------------------------------------------------------
__global__ __launch_bounds__(256)
void dwconv_k(const float* __restrict__ in, const float* __restrict__ cw,
              const float* __restrict__ cb, float* __restrict__ out) {
    __shared__ float wl[128 * 49];
    const int tid = threadIdx.x;
    for (int i = tid; i < 128 * 49; i += 256) wl[i] = cw[i];
    __syncthreads();
    const int c = tid & 127;
    const int w = blockIdx.x * 2 + (tid >> 7);
    const int h = blockIdx.y;
    const int b = blockIdx.z;
    const float* ib = in + ((size_t)b * HW_) * 128 + c;
    const float* wc = &wl[c * 49];
    float acc = cb[c];
    for (int ky = 0; ky < 7; ++ky) {
        const int y = h + ky - 3;
        if ((unsigned)y >= (unsigned)HGT) continue;
        const size_t ro = (size_t)y * WID * 128;
        for (int kx = 0; kx < 7; ++kx) {
            const int x = w + kx - 3;
            if ((unsigned)x >= (unsigned)WID) continue;
            acc += ib[ro + (size_t)x * 128] * wc[ky * 7 + kx];
        }
    }
    out[((size_t)(b * HW_ + h * WID + w)) * 128 + c] = acc;
}

// ---------------------------------------------------------------------------
extern "C" void kernel_launch(void* const* d_in, const int* in_sizes, int n_in,
                              void* d_out, int out_size, void* d_ws, size_t ws_size,
                              hipStream_t stream) {
    const float* x      = (const float*)d_in[0];
    const float* x_e    = (const float*)d_in[1];
    const float* norm_w = (const float*)d_in[2];
    const float* norm_b = (const float*)d_in[3];
    const float* norme_w= (const float*)d_in[4];
    const float* norme_b= (const float*)d_in[5];
    const float* l_w    = (const float*)d_in[6];
    const float* l_b    = (const float*)d_in[7];
    const float* kv_w   = (const float*)d_in[8];
    const float* kv_b   = (const float*)d_in[9];
    const float* xe_w   = (const float*)d_in[10];
    const float* xe_b   = (const float*)d_in[11];
    const float* q_w    = (const float*)d_in[12];
    const float* q_b    = (const float*)d_in[13];
    const float* ef_w   = (const float*)d_in[14];
    const float* ef_b   = (const float*)d_in[15];
    const float* ec_w   = (const float*)d_in[16];
    const float* ec_b   = (const float*)d_in[17];
    const float* eb_w   = (const float*)d_in[18];
    const float* eb_b   = (const float*)d_in[19];
    const float* proj_w = (const float*)d_in[20];
    const float* proj_b = (const float*)d_in[21];
    const float* proje_w= (const float*)d_in[22];
    const float* proje_b= (const float*)d_in[23];
    float* out = (float*)d_out;

    float* ws = (float*)d_ws;
    const size_t MS = (size_t)MROWS * 256;   // 35,684,352 floats
    const size_t MH = (size_t)MROWS * 128;
    float* P0 = ws;                // xcl  (M,256)
    float* P1 = ws + MS;           // xel  (M,256)
    float* P2 = ws + 2 * MS;       // xg ; later P2a=ef/g, P2b=conv
    float* P3 = ws + 3 * MS;       // kv ; later P3a=l1, P3b=l2
    float* pooled = ws + 4 * MS;   // 147456
    float* mbuf = pooled + 147456; // 36864
    float* aout = mbuf + 36864;    // 36864
    float* P2a = P2;
    float* P2b = P2 + MH;
    float* P3a = P3;
    float* P3b = P3 + MH;

    const dim3 blk(256);
    // 1. LayerNorms (transpose to channels-last)
    ln_k<<<dim3(HW_ / 4, 8), blk, 0, stream>>>(x, norm_w, norm_b, P0);
    ln_k<<<dim3(HW_ / 4, 8), blk, 0, stream>>>(x_e, norme_w, norme_b, P1);
    // 2. xg = gelu(xcl @ l_w + l_b)
    gemm_k<1><<<dim3(MROWS / 128, 4), blk, 0, stream>>>(P0, l_w, l_b, P2, nullptr, 256, 256);
    // 3. kv = xg @ kv_w + kv_b
    gemm_k<0><<<dim3(MROWS / 128, 4), blk, 0, stream>>>(P2, kv_w, kv_b, P3, nullptr, 256, 256);
    // 4. pooled 6x6 of cat
    pool_k<<<dim3(36, 8), blk, 0, stream>>>(P0, P1, pooled);
    // 5. m projection
    mproj_k<<<dim3(36, 8), dim3(128), 0, stream>>>(pooled, xe_w, xe_b, mbuf);
    // 6. attention -> aout (B,8,36,16)
    attn_k<<<dim3(36, 8, 8), blk, 0, stream>>>(mbuf, P3, aout);
    // 7. LFA1: ef1 = xel @ ef_w -> P2a ; conv -> P2b ; q1 -> P3a ; l1 = e*q -> P3a
    gemm_k<0><<<dim3(MROWS / 128, 2), blk, 0, stream>>>(P1, ef_w, ef_b, P2a, nullptr, 256, 128);
    dwconv_k<<<dim3(WID / 2, HGT, 8), blk, 0, stream>>>(P2a, ec_w, ec_b, P2b);
    gemm_k<0><<<dim3(MROWS / 128, 2), blk, 0, stream>>>(P0, q_w, q_b, P3a, nullptr, 256, 128);
    gemm_k<2><<<dim3(MROWS / 128, 2), blk, 0, stream>>>(P2b, eb_w, eb_b, P3a, P3a, 128, 128);
    // 8. LFA2 (swapped inputs) -> P3b
    gemm_k<0><<<dim3(MROWS / 128, 2), blk, 0, stream>>>(P0, ef_w, ef_b, P2a, nullptr, 256, 128);
    dwconv_k<<<dim3(WID / 2, HGT, 8), blk, 0, stream>>>(P2a, ec_w, ec_b, P2b);
    gemm_k<0><<<dim3(MROWS / 128, 2), blk, 0, stream>>>(P1, q_w, q_b, P3b, nullptr, 256, 128);
    gemm_k<2><<<dim3(MROWS / 128, 2), blk, 0, stream>>>(P2b, eb_w, eb_b, P3b, P3b, 128, 128);
    // 9. g = upsample(attention out) -> P2a
    upsample_k<<<dim3(HW_ / 2, 8), blk, 0, stream>>>(aout, P2a);
    // 10. fused final projection -> d_out (out, out_e)
    gemm_proj_k<<<dim3(MROWS / 128, 8), blk, 0, stream>>>(
        P2a, P3a, P3b, proj_w, proj_b, proje_w, proje_b, out);
}